// Round 2
// baseline (3678.777 us; speedup 1.0000x reference)
//
#include <hip/hip_runtime.h>

#define B_   64
#define T_   4096
#define HID_ 128

typedef float f32x4 __attribute__((ext_vector_type(4)));
typedef short s16x8 __attribute__((ext_vector_type(8)));
typedef short s16x4 __attribute__((ext_vector_type(4)));

__device__ __forceinline__ float fexp2(float x){ float r; asm("v_exp_f32 %0, %1":"=v"(r):"v"(x)); return r; }
__device__ __forceinline__ float frcp (float x){ float r; asm("v_rcp_f32 %0, %1":"=v"(r):"v"(x)); return r; }
__device__ __forceinline__ unsigned short f2bf(float f){
    unsigned u = __float_as_uint(f);
    u += 0x7FFFu + ((u >> 16) & 1u);      // round-to-nearest-even
    return (unsigned short)(u >> 16);
}
__device__ __forceinline__ float sigf(float x){
    return frcp(1.0f + fexp2(-1.44269504089f * x));
}

// ---------------- Phase 1: ODE features -> feats[B][T][32] bf16 ----------------
__global__ __launch_bounds__(256) void k_feats(
    const float* __restrict__ x, const float* __restrict__ u,
    const float* __restrict__ dtp, const float* __restrict__ theta,
    const float* __restrict__ He, const float* __restrict__ taue,
    const float* __restrict__ Hi, const float* __restrict__ taui,
    const float* __restrict__ l1, const float* __restrict__ l2,
    const float* __restrict__ l3, const float* __restrict__ l4,
    const float* __restrict__ Cf, const float* __restrict__ Cl,
    const float* __restrict__ Cu, const float* __restrict__ Cb,
    unsigned short* __restrict__ feats)
{
    long idx = (long)blockIdx.x * 256 + threadIdx.x;   // b*T + t
    const float dt = dtp[0];
    const float th00 = theta[0], th01 = theta[1], th10 = theta[2], th11 = theta[3];
    const float he = He[0], te = taue[0], hi = Hi[0], ti = taui[0];
    const float L1 = l1[0], L2v = l2[0], L3 = l3[0], L4 = l4[0];
    float cf[4], cl[4], cu[4], cb[4];
    #pragma unroll
    for (int i = 0; i < 4; ++i){ cf[i]=Cf[i]; cl[i]=Cl[i]; cu[i]=Cu[i]; cb[i]=Cb[i]; }
    const float ite  = 1.f/te, iti = 1.f/ti;
    const float He_te = he*ite, ite2 = ite*ite;
    const float Hi_ti = hi*iti, iti2 = iti*iti;

    float X[22];
    const float2* xr = (const float2*)(x + idx*22);
    #pragma unroll
    for (int i = 0; i < 11; ++i){ float2 v = xr[i]; X[2*i] = v.x; X[2*i+1] = v.y; }
    float2 uv = ((const float2*)u)[idx];

    float xt0 = X[0]*th00 + X[1]*th10;     // x[...,0,:] @ theta  ('btn,nm')
    float xt1 = X[0]*th01 + X[1]*th11;
    float ut0 = uv.x*th00 + uv.y*th10;
    float ut1 = uv.x*th01 + uv.y*th11;
    float s0 = sigf(xt0), s1 = sigf(xt1);

    // 'btn,mn->btm' : out[m] = sum_n M[m][n]*v[n]
    float Mf00 = cf[0]+cl[0]+L1, Mf01 = cf[1]+cl[1], Mf10 = cf[2]+cl[2], Mf11 = cf[3]+cl[3]+L1;
    float Af0 = Mf00*s0 + Mf01*s1, Af1 = Mf10*s0 + Mf11*s1;
    float Au0 = cu[0]*ut0 + cu[1]*ut1, Au1 = cu[2]*ut0 + cu[3]*ut1;
    float Mb00 = cb[0]+cl[0], Mb01 = cb[1]+cl[1], Mb10 = cb[2]+cl[2], Mb11 = cb[3]+cl[3];
    float Abl0 = Mb00*s0 + Mb01*s1, Abl1 = Mb10*s0 + Mb11*s1;
    float A30 = (Mb00+L3)*s0 + Mb01*s1,  A31 = Mb10*s0 + (Mb11+L3)*s1;

    float F[22];
    F[0]  = X[0]  + dt*(X[10]-X[12]);
    F[1]  = X[1]  + dt*(X[11]-X[13]);
    F[2]  = X[2]  + dt*X[8];
    F[3]  = X[3]  + dt*X[9];
    F[4]  = X[4]  + dt*X[10];
    F[5]  = X[5]  + dt*X[11];
    F[6]  = X[6]  + dt*X[12];
    F[7]  = X[7]  + dt*X[13];
    F[8]  = X[8]  + dt*(He_te*(Af0+Au0) - 2.f*X[8]*ite  - X[2]*ite2);
    F[9]  = X[9]  + dt*(He_te*(Af1+Au1) - 2.f*X[9]*ite  - X[3]*ite2);
    F[10] = X[10] + dt*(He_te*(Abl0 + L2v*sigf(X[6])) - 2.f*X[10]*ite - X[4]*ite2);
    F[11] = X[11] + dt*(He_te*(Abl1 + L2v*sigf(X[7])) - 2.f*X[11]*ite - X[5]*ite2);
    F[12] = X[12] + dt*(Hi_ti*L4*sigf(X[14]) - 2.f*X[12]*iti - X[6]*iti2);
    F[13] = X[13] + dt*(Hi_ti*L4*sigf(X[15]) - 2.f*X[13]*iti - X[7]*iti2);
    F[14] = X[14] + dt*X[16];
    F[15] = X[15] + dt*X[17];
    F[16] = X[16] + dt*(He_te*A30 - 2.f*X[16]*ite - X[14]*ite2);
    F[17] = X[17] + dt*(He_te*A31 - 2.f*X[17]*ite - X[15]*ite2);
    F[18] = X[18]; F[19] = X[19]; F[20] = X[20]; F[21] = X[21];

    unsigned short o[32];
    #pragma unroll
    for (int i = 0; i < 22; ++i) o[i] = f2bf(F[i]);
    #pragma unroll
    for (int i = 22; i < 32; ++i) o[i] = 0;
    uint4* dst = (uint4*)(feats + idx*32);
    #pragma unroll
    for (int q = 0; q < 4; ++q){
        uint4 v;
        v.x = (unsigned)o[q*8+0] | ((unsigned)o[q*8+1] << 16);
        v.y = (unsigned)o[q*8+2] | ((unsigned)o[q*8+3] << 16);
        v.z = (unsigned)o[q*8+4] | ((unsigned)o[q*8+5] << 16);
        v.w = (unsigned)o[q*8+6] | ((unsigned)o[q*8+7] << 16);
        dst[q] = v;
    }
}

// ---------------- Phase 2: LSTM scan + fused W_lin head ----------------
// 16 blocks x 4 batches. 512 threads = 8 waves; wave w owns j in [w*16, w*16+16).
// Batch b sits at MFMA A-row 4b. Only lanes with (l&3)==0 carry real A data ->
// only they load; other lanes' stale frags land in unused D rows (MFMA is row-exact).
// LDS: h-only, 4 rows (batches) x 144 shorts (288B stride, conflict-free for the
// 16 active lanes). feats come straight from global with depth-2 reg prefetch.
// Waves 6/7 compute y(t-1) from lbuf h (off the compute critical path).
__global__ __launch_bounds__(512, 2) void k_scan(
    const unsigned short* __restrict__ feats,
    const float* __restrict__ Wih, const float* __restrict__ Whh,
    const float* __restrict__ bih, const float* __restrict__ bhh,
    const float* __restrict__ Wlin, const float* __restrict__ blin,
    float* __restrict__ out)
{
    __shared__ __align__(16) unsigned short lbuf[2][4*144];

    const int tid = threadIdx.x;
    const int w  = tid >> 6;
    const int l  = tid & 63;
    const int lm = l & 15;          // A/D column-lane
    const int lg = l >> 4;          // lane group -> batch for activations
    const int gb0 = blockIdx.x * 4;
    const bool act = (l & 3) == 0;  // lanes carrying real A rows {0,4,8,12}
    const int ar  = lm >> 2;        // batch index of this A row (valid when act)

    // zero LDS (h(-1) = 0 in buf0; buf1 fully rewritten each step anyway)
    for (int i = tid; i < (int)(sizeof(lbuf)/4); i += 512) ((unsigned*)lbuf)[i] = 0u;

    // ---- pack weight B-fragments into registers (bf16) ----
    const int nj = w*16 + lm;       // this thread's hidden index j
    s16x8 bw[4][5];
    #pragma unroll
    for (int t4 = 0; t4 < 4; ++t4){
        int n = t4*128 + nj;        // gate row: i,f,g,o blocks of 128
        #pragma unroll
        for (int kc = 0; kc < 5; ++kc){
            #pragma unroll
            for (int j = 0; j < 8; ++j){
                int k = kc*32 + lg*4 + (j & 3) + ((j >> 2) << 4);
                float wv = 0.f;
                if (kc == 0){ if (k < 22) wv = Wih[n*22 + k]; }
                else        { wv = Whh[n*128 + (k - 32)]; }
                bw[t4][kc][j] = (short)f2bf(wv);
            }
        }
    }
    const float L2E = 1.44269504089f;
    float nLb0, nLb1, nLb3, b2g;
    {
        float bi = bih[0*128+nj] + bhh[0*128+nj];
        float bf = bih[1*128+nj] + bhh[1*128+nj];
        float bg = bih[2*128+nj] + bhh[2*128+nj];
        float bo = bih[3*128+nj] + bhh[3*128+nj];
        nLb0 = -L2E*bi; nLb1 = -L2E*bf; nLb3 = -L2E*bo; b2g = 2.f*L2E*bg;
    }
    // y waves (6,7): W_lin slices; lane (l&15) covers j = (l&15)*8 .. +7
    float wly0[8], wly1[8];
    float bl0 = 0.f, bl1 = 0.f;
    if (w >= 6 && l < 32){
        int jb = (l & 15) * 8;
        #pragma unroll
        for (int e = 0; e < 8; ++e){ wly0[e] = Wlin[jb+e]; wly1[e] = Wlin[128+jb+e]; }
        bl0 = blin[0]; bl1 = blin[1];
    } else {
        #pragma unroll
        for (int e = 0; e < 8; ++e){ wly0[e] = 0.f; wly1[e] = 0.f; }
    }

    __syncthreads();   // zeroing visible

    // feats prefetch (active lanes only), depth-2 ping-pong
    const unsigned short* fbase = feats + ((long)(gb0 + ar) * T_) * 32 + lg*4;
    s16x4 pflA = {0,0,0,0}, pfhA = {0,0,0,0}, pflB = {0,0,0,0}, pfhB = {0,0,0,0};
    if (act){
        pflA = *(const s16x4*)(fbase + 0*32);
        pfhA = *(const s16x4*)(fbase + 0*32 + 16);
        pflB = *(const s16x4*)(fbase + 1*32);
        pfhB = *(const s16x4*)(fbase + 1*32 + 16);
    }

    const f32x4 Z4 = {0.f, 0.f, 0.f, 0.f};
    s16x8 af0 = {0,0,0,0,0,0,0,0}, af1 = af0, af2 = af0, af3 = af0, af4 = af0;
    float c = 0.f;

    for (int t = 0; t < T_; ++t){
        const int cur = t & 1;
        const unsigned short* hb = lbuf[cur];

        if (act){
            const char* bp = (const char*)hb + ar*288 + lg*8;
            s16x4 a1l = *(const s16x4*)(bp +   0), a1h = *(const s16x4*)(bp +  32);
            s16x4 a2l = *(const s16x4*)(bp +  64), a2h = *(const s16x4*)(bp +  96);
            s16x4 a3l = *(const s16x4*)(bp + 128), a3h = *(const s16x4*)(bp + 160);
            s16x4 a4l = *(const s16x4*)(bp + 192), a4h = *(const s16x4*)(bp + 224);
            af1 = (s16x8){a1l[0],a1l[1],a1l[2],a1l[3],a1h[0],a1h[1],a1h[2],a1h[3]};
            af2 = (s16x8){a2l[0],a2l[1],a2l[2],a2l[3],a2h[0],a2h[1],a2h[2],a2h[3]};
            af3 = (s16x8){a3l[0],a3l[1],a3l[2],a3l[3],a3h[0],a3h[1],a3h[2],a3h[3]};
            af4 = (s16x8){a4l[0],a4l[1],a4l[2],a4l[3],a4h[0],a4h[1],a4h[2],a4h[3]};
            if ((t & 1) == 0){
                af0 = (s16x8){pflA[0],pflA[1],pflA[2],pflA[3],pfhA[0],pfhA[1],pfhA[2],pfhA[3]};
                long o = (long)((t+2 < T_) ? t+2 : T_-1) * 32;
                pflA = *(const s16x4*)(fbase + o);
                pfhA = *(const s16x4*)(fbase + o + 16);
            } else {
                af0 = (s16x8){pflB[0],pflB[1],pflB[2],pflB[3],pfhB[0],pfhB[1],pfhB[2],pfhB[3]};
                long o = (long)((t+2 < T_) ? t+2 : T_-1) * 32;
                pflB = *(const s16x4*)(fbase + o);
                pfhB = *(const s16x4*)(fbase + o + 16);
            }
        }

        // 4 gates x (chain A: feats+h0+h1, chain B: h2+h3) -> 8 independent chains
        f32x4 aA0 = __builtin_amdgcn_mfma_f32_16x16x32_bf16(af0, bw[0][0], Z4, 0,0,0);
        f32x4 aA1 = __builtin_amdgcn_mfma_f32_16x16x32_bf16(af0, bw[1][0], Z4, 0,0,0);
        f32x4 aA2 = __builtin_amdgcn_mfma_f32_16x16x32_bf16(af0, bw[2][0], Z4, 0,0,0);
        f32x4 aA3 = __builtin_amdgcn_mfma_f32_16x16x32_bf16(af0, bw[3][0], Z4, 0,0,0);
        f32x4 aB0 = __builtin_amdgcn_mfma_f32_16x16x32_bf16(af3, bw[0][3], Z4, 0,0,0);
        f32x4 aB1 = __builtin_amdgcn_mfma_f32_16x16x32_bf16(af3, bw[1][3], Z4, 0,0,0);
        f32x4 aB2 = __builtin_amdgcn_mfma_f32_16x16x32_bf16(af3, bw[2][3], Z4, 0,0,0);
        f32x4 aB3 = __builtin_amdgcn_mfma_f32_16x16x32_bf16(af3, bw[3][3], Z4, 0,0,0);
        aA0 = __builtin_amdgcn_mfma_f32_16x16x32_bf16(af1, bw[0][1], aA0, 0,0,0);
        aA1 = __builtin_amdgcn_mfma_f32_16x16x32_bf16(af1, bw[1][1], aA1, 0,0,0);
        aA2 = __builtin_amdgcn_mfma_f32_16x16x32_bf16(af1, bw[2][1], aA2, 0,0,0);
        aA3 = __builtin_amdgcn_mfma_f32_16x16x32_bf16(af1, bw[3][1], aA3, 0,0,0);
        aB0 = __builtin_amdgcn_mfma_f32_16x16x32_bf16(af4, bw[0][4], aB0, 0,0,0);
        aB1 = __builtin_amdgcn_mfma_f32_16x16x32_bf16(af4, bw[1][4], aB1, 0,0,0);
        aB2 = __builtin_amdgcn_mfma_f32_16x16x32_bf16(af4, bw[2][4], aB2, 0,0,0);
        aB3 = __builtin_amdgcn_mfma_f32_16x16x32_bf16(af4, bw[3][4], aB3, 0,0,0);
        aA0 = __builtin_amdgcn_mfma_f32_16x16x32_bf16(af2, bw[0][2], aA0, 0,0,0);
        aA1 = __builtin_amdgcn_mfma_f32_16x16x32_bf16(af2, bw[1][2], aA1, 0,0,0);
        aA2 = __builtin_amdgcn_mfma_f32_16x16x32_bf16(af2, bw[2][2], aA2, 0,0,0);
        aA3 = __builtin_amdgcn_mfma_f32_16x16x32_bf16(af2, bw[3][2], aA3, 0,0,0);

        // y waves: finish y(t-1) from h(t-1) sitting in lbuf[cur]
        if (w >= 6 && l < 32 && t > 0){
            int b = (w - 6)*2 + (l >> 4);
            s16x8 hv = *(const s16x8*)(hb + b*144 + (l & 15)*8);
            float y0 = 0.f, y1 = 0.f;
            #pragma unroll
            for (int e = 0; e < 8; ++e){
                float hf = __uint_as_float(((unsigned)(unsigned short)hv[e]) << 16);
                y0 = fmaf(hf, wly0[e], y0); y1 = fmaf(hf, wly1[e], y1);
            }
            #pragma unroll
            for (int m = 1; m < 16; m <<= 1){ y0 += __shfl_xor(y0, m); y1 += __shfl_xor(y1, m); }
            if ((l & 15) == 0){
                float2 yv; yv.x = y0 + bl0; yv.y = y1 + bl1;
                *(float2*)&out[((long)(gb0 + b)*T_ + (t-1))*2] = yv;
            }
        }

        // activations: this thread's (b,j) = (lg, nj)
        float gi = aA0[0] + aB0[0];
        float gf = aA1[0] + aB1[0];
        float gg = aA2[0] + aB2[0];
        float go = aA3[0] + aB3[0];
        float si = frcp(1.f + fexp2(fmaf(gi, -L2E, nLb0)));
        float sf = frcp(1.f + fexp2(fmaf(gf, -L2E, nLb1)));
        float so = frcp(1.f + fexp2(fmaf(go, -L2E, nLb3)));
        float eg = fexp2(fmaf(gg, 2.f*L2E, b2g));
        float tg = fmaf(-2.f, frcp(1.f + eg), 1.f);
        c = sf*c + si*tg;
        float ec = fexp2(c * (2.f*L2E));
        float tc = fmaf(-2.f, frcp(1.f + ec), 1.f);
        float h = so * tc;

        // write h (bf16) for next step: row lg, col j
        unsigned hp;
        asm("v_cvt_pk_bf16_f32 %0, %1, %1" : "=v"(hp) : "v"(h));
        ((unsigned short*)lbuf[cur ^ 1])[lg*144 + nj] = (unsigned short)hp;

        __syncthreads();
    }

    // epilogue: y(T-1); h(T-1) sits in lbuf[0] (T_ even)
    if (w >= 6 && l < 32){
        int b = (w - 6)*2 + (l >> 4);
        const unsigned short* hb = lbuf[0];
        s16x8 hv = *(const s16x8*)(hb + b*144 + (l & 15)*8);
        float y0 = 0.f, y1 = 0.f;
        #pragma unroll
        for (int e = 0; e < 8; ++e){
            float hf = __uint_as_float(((unsigned)(unsigned short)hv[e]) << 16);
            y0 = fmaf(hf, wly0[e], y0); y1 = fmaf(hf, wly1[e], y1);
        }
        #pragma unroll
        for (int m = 1; m < 16; m <<= 1){ y0 += __shfl_xor(y0, m); y1 += __shfl_xor(y1, m); }
        if ((l & 15) == 0){
            float2 yv; yv.x = y0 + bl0; yv.y = y1 + bl1;
            *(float2*)&out[((long)(gb0 + b)*T_ + (T_-1))*2] = yv;
        }
    }
}

extern "C" void kernel_launch(void* const* d_in, const int* in_sizes, int n_in,
                              void* d_out, int out_size, void* d_ws, size_t ws_size,
                              hipStream_t stream)
{
    const float* x     = (const float*)d_in[0];
    const float* u     = (const float*)d_in[1];
    const float* dtp   = (const float*)d_in[2];
    const float* theta = (const float*)d_in[3];
    const float* He    = (const float*)d_in[4];
    const float* taue  = (const float*)d_in[5];
    const float* Hi    = (const float*)d_in[6];
    const float* taui  = (const float*)d_in[7];
    const float* l1    = (const float*)d_in[8];
    const float* l2    = (const float*)d_in[9];
    const float* l3    = (const float*)d_in[10];
    const float* l4    = (const float*)d_in[11];
    const float* Cf    = (const float*)d_in[12];
    const float* Cl    = (const float*)d_in[13];
    const float* Cu    = (const float*)d_in[14];
    const float* Cb    = (const float*)d_in[15];
    const float* Wih   = (const float*)d_in[16];
    const float* Whh   = (const float*)d_in[17];
    const float* bih   = (const float*)d_in[18];
    const float* bhh   = (const float*)d_in[19];
    const float* Wlin  = (const float*)d_in[20];
    const float* blin  = (const float*)d_in[21];

    unsigned short* feats = (unsigned short*)d_ws;   // B*T*32 bf16 = 16 MiB

    k_feats<<<(B_*T_)/256, 256, 0, stream>>>(x,u,dtp,theta,He,taue,Hi,taui,
                                             l1,l2,l3,l4,Cf,Cl,Cu,Cb,feats);
    k_scan<<<16, 512, 0, stream>>>(feats, Wih, Whh, bih, bhh, Wlin, blin, (float*)d_out);
}

// Round 3
// 3458.171 us; speedup vs baseline: 1.0638x; 1.0638x over previous
//
#include <hip/hip_runtime.h>

#define B_   64
#define T_   4096
#define HID_ 128
#define CH_  256   // steps per feats chunk (T_ % CH_ == 0)

typedef float f32x4 __attribute__((ext_vector_type(4)));
typedef short s16x8 __attribute__((ext_vector_type(8)));
typedef short s16x4 __attribute__((ext_vector_type(4)));

__device__ __forceinline__ float fexp2(float x){ float r; asm("v_exp_f32 %0, %1":"=v"(r):"v"(x)); return r; }
__device__ __forceinline__ float frcp (float x){ float r; asm("v_rcp_f32 %0, %1":"=v"(r):"v"(x)); return r; }
__device__ __forceinline__ unsigned short f2bf(float f){
    unsigned u = __float_as_uint(f);
    u += 0x7FFFu + ((u >> 16) & 1u);      // round-to-nearest-even
    return (unsigned short)(u >> 16);
}
__device__ __forceinline__ float sigf(float x){
    return frcp(1.0f + fexp2(-1.44269504089f * x));
}

// ---------------- Phase 1: ODE features -> feats[B][T][32] bf16 ----------------
__global__ __launch_bounds__(256) void k_feats(
    const float* __restrict__ x, const float* __restrict__ u,
    const float* __restrict__ dtp, const float* __restrict__ theta,
    const float* __restrict__ He, const float* __restrict__ taue,
    const float* __restrict__ Hi, const float* __restrict__ taui,
    const float* __restrict__ l1, const float* __restrict__ l2,
    const float* __restrict__ l3, const float* __restrict__ l4,
    const float* __restrict__ Cf, const float* __restrict__ Cl,
    const float* __restrict__ Cu, const float* __restrict__ Cb,
    unsigned short* __restrict__ feats)
{
    long idx = (long)blockIdx.x * 256 + threadIdx.x;   // b*T + t
    const float dt = dtp[0];
    const float th00 = theta[0], th01 = theta[1], th10 = theta[2], th11 = theta[3];
    const float he = He[0], te = taue[0], hi = Hi[0], ti = taui[0];
    const float L1 = l1[0], L2v = l2[0], L3 = l3[0], L4 = l4[0];
    float cf[4], cl[4], cu[4], cb[4];
    #pragma unroll
    for (int i = 0; i < 4; ++i){ cf[i]=Cf[i]; cl[i]=Cl[i]; cu[i]=Cu[i]; cb[i]=Cb[i]; }
    const float ite  = 1.f/te, iti = 1.f/ti;
    const float He_te = he*ite, ite2 = ite*ite;
    const float Hi_ti = hi*iti, iti2 = iti*iti;

    float X[22];
    const float2* xr = (const float2*)(x + idx*22);
    #pragma unroll
    for (int i = 0; i < 11; ++i){ float2 v = xr[i]; X[2*i] = v.x; X[2*i+1] = v.y; }
    float2 uv = ((const float2*)u)[idx];

    float xt0 = X[0]*th00 + X[1]*th10;     // x[...,0,:] @ theta  ('btn,nm')
    float xt1 = X[0]*th01 + X[1]*th11;
    float ut0 = uv.x*th00 + uv.y*th10;
    float ut1 = uv.x*th01 + uv.y*th11;
    float s0 = sigf(xt0), s1 = sigf(xt1);

    // 'btn,mn->btm' : out[m] = sum_n M[m][n]*v[n]
    float Mf00 = cf[0]+cl[0]+L1, Mf01 = cf[1]+cl[1], Mf10 = cf[2]+cl[2], Mf11 = cf[3]+cl[3]+L1;
    float Af0 = Mf00*s0 + Mf01*s1, Af1 = Mf10*s0 + Mf11*s1;
    float Au0 = cu[0]*ut0 + cu[1]*ut1, Au1 = cu[2]*ut0 + cu[3]*ut1;
    float Mb00 = cb[0]+cl[0], Mb01 = cb[1]+cl[1], Mb10 = cb[2]+cl[2], Mb11 = cb[3]+cl[3];
    float Abl0 = Mb00*s0 + Mb01*s1, Abl1 = Mb10*s0 + Mb11*s1;
    float A30 = (Mb00+L3)*s0 + Mb01*s1,  A31 = Mb10*s0 + (Mb11+L3)*s1;

    float F[22];
    F[0]  = X[0]  + dt*(X[10]-X[12]);
    F[1]  = X[1]  + dt*(X[11]-X[13]);
    F[2]  = X[2]  + dt*X[8];
    F[3]  = X[3]  + dt*X[9];
    F[4]  = X[4]  + dt*X[10];
    F[5]  = X[5]  + dt*X[11];
    F[6]  = X[6]  + dt*X[12];
    F[7]  = X[7]  + dt*X[13];
    F[8]  = X[8]  + dt*(He_te*(Af0+Au0) - 2.f*X[8]*ite  - X[2]*ite2);
    F[9]  = X[9]  + dt*(He_te*(Af1+Au1) - 2.f*X[9]*ite  - X[3]*ite2);
    F[10] = X[10] + dt*(He_te*(Abl0 + L2v*sigf(X[6])) - 2.f*X[10]*ite - X[4]*ite2);
    F[11] = X[11] + dt*(He_te*(Abl1 + L2v*sigf(X[7])) - 2.f*X[11]*ite - X[5]*ite2);
    F[12] = X[12] + dt*(Hi_ti*L4*sigf(X[14]) - 2.f*X[12]*iti - X[6]*iti2);
    F[13] = X[13] + dt*(Hi_ti*L4*sigf(X[15]) - 2.f*X[13]*iti - X[7]*iti2);
    F[14] = X[14] + dt*X[16];
    F[15] = X[15] + dt*X[17];
    F[16] = X[16] + dt*(He_te*A30 - 2.f*X[16]*ite - X[14]*ite2);
    F[17] = X[17] + dt*(He_te*A31 - 2.f*X[17]*ite - X[15]*ite2);
    F[18] = X[18]; F[19] = X[19]; F[20] = X[20]; F[21] = X[21];

    unsigned short o[32];
    #pragma unroll
    for (int i = 0; i < 22; ++i) o[i] = f2bf(F[i]);
    #pragma unroll
    for (int i = 22; i < 32; ++i) o[i] = 0;
    uint4* dst = (uint4*)(feats + idx*32);
    #pragma unroll
    for (int q = 0; q < 4; ++q){
        uint4 v;
        v.x = (unsigned)o[q*8+0] | ((unsigned)o[q*8+1] << 16);
        v.y = (unsigned)o[q*8+2] | ((unsigned)o[q*8+3] << 16);
        v.z = (unsigned)o[q*8+4] | ((unsigned)o[q*8+5] << 16);
        v.w = (unsigned)o[q*8+6] | ((unsigned)o[q*8+7] << 16);
        dst[q] = v;
    }
}

// ---------------- Phase 2: LSTM scan + fused W_lin head ----------------
// 16 blocks x 4 batches, 512 threads = 8 waves; wave w owns j in [w*16, w*16+16).
// Batch b sits at MFMA A-row 4b. Only lanes (l&3)==0 carry real A rows {0,4,8,12}.
// PURE-LDS step loop: feats staged in 64KB LDS chunks (CH_ steps), y buffered in
// LDS and flushed per chunk -> per-step __syncthreads has no vmem to drain.
// af0 (feats frag) is software-prefetched one step ahead from the chunk buffer.
__global__ __launch_bounds__(512, 1) void k_scan(
    const unsigned short* __restrict__ feats,
    const float* __restrict__ Wih, const float* __restrict__ Whh,
    const float* __restrict__ bih, const float* __restrict__ bhh,
    const float* __restrict__ Wlin, const float* __restrict__ blin,
    float* __restrict__ out)
{
    __shared__ __align__(16) unsigned short fch[CH_ * 128];     // [tc][b][32] bf16, 64KB
    __shared__ __align__(16) unsigned short lbuf[2][4*144];     // h double buffer
    __shared__ __align__(16) float ybuf[4 * 2 * CH_];           // [b][slot][o], slot tc = y(t-1)

    const int tid = threadIdx.x;
    const int w  = tid >> 6;
    const int l  = tid & 63;
    const int lm = l & 15;          // A/D column-lane
    const int lg = l >> 4;          // lane group -> batch for activations
    const int gb0 = blockIdx.x * 4;
    const bool act = (l & 3) == 0;  // lanes carrying real A rows {0,4,8,12}
    const int ar  = lm >> 2;        // batch index of this A row (valid when act)

    // zero h buffers (h(-1) = 0)
    for (int i = tid; i < (int)(sizeof(lbuf)/4); i += 512) ((unsigned*)lbuf)[i] = 0u;

    // ---- pack weight B-fragments into registers (bf16) ----
    const int nj = w*16 + lm;       // this thread's hidden index j
    s16x8 bw[4][5];
    #pragma unroll
    for (int t4 = 0; t4 < 4; ++t4){
        int n = t4*128 + nj;        // gate row: i,f,g,o blocks of 128
        #pragma unroll
        for (int kc = 0; kc < 5; ++kc){
            #pragma unroll
            for (int j = 0; j < 8; ++j){
                int k = kc*32 + lg*4 + (j & 3) + ((j >> 2) << 4);
                float wv = 0.f;
                if (kc == 0){ if (k < 22) wv = Wih[n*22 + k]; }
                else        { wv = Whh[n*128 + (k - 32)]; }
                bw[t4][kc][j] = (short)f2bf(wv);
            }
        }
    }
    const float L2E = 1.44269504089f;
    float nLb0, nLb1, nLb3, b2g;
    {
        float bi = bih[0*128+nj] + bhh[0*128+nj];
        float bf = bih[1*128+nj] + bhh[1*128+nj];
        float bg = bih[2*128+nj] + bhh[2*128+nj];
        float bo = bih[3*128+nj] + bhh[3*128+nj];
        nLb0 = -L2E*bi; nLb1 = -L2E*bf; nLb3 = -L2E*bo; b2g = 2.f*L2E*bg;
    }
    // y waves (6,7): W_lin slices; lane (l&15) covers j = (l&15)*8 .. +7
    float wly0[8], wly1[8];
    float bl0 = 0.f, bl1 = 0.f;
    if (w >= 6 && l < 32){
        int jb = (l & 15) * 8;
        #pragma unroll
        for (int e = 0; e < 8; ++e){ wly0[e] = Wlin[jb+e]; wly1[e] = Wlin[128+jb+e]; }
        bl0 = blin[0]; bl1 = blin[1];
    } else {
        #pragma unroll
        for (int e = 0; e < 8; ++e){ wly0[e] = 0.f; wly1[e] = 0.f; }
    }

    const f32x4 Z4 = {0.f, 0.f, 0.f, 0.f};
    s16x8 af0 = {0,0,0,0,0,0,0,0};
    float c = 0.f;

    for (int chk = 0; chk < T_/CH_; ++chk){
        const int c0 = chk * CH_;

        // ---- flush previous chunk's y buffer (slot s = y(c0p + s - 1)) ----
        if (chk > 0){
            const int c0p = c0 - CH_;
            int b = tid >> 7, i = tid & 127;           // i indexes float4 = slots 2i,2i+1
            long tg = (long)c0p + 2*i - 1;
            const float* src = &ybuf[b*(2*CH_) + i*4];
            if (tg >= 0){
                float2 v0 = *(const float2*)(src);
                float2 v1 = *(const float2*)(src + 2);
                float* dst = &out[((long)(gb0+b)*T_ + tg)*2];
                *(float2*)dst = v0; *(float2*)(dst + 2) = v1;
            } else {                                    // chunk 0, slot 0 is t=-1: emit y(0) only
                float2 v1 = *(const float2*)(src + 2);
                *(float2*)&out[((long)(gb0+b)*T_)*2] = v1;
            }
        }

        // ---- stage feats chunk: global -> fch (linear, 16B units) ----
        #pragma unroll
        for (int it = 0; it < (CH_*128*2/16)/512; ++it){
            int uu = tid + it*512;                      // 16B unit
            int t_loc = uu >> 4, rem = uu & 15, b = rem >> 2, q = rem & 3;
            uint4 v = *(const uint4*)(feats + ((long)(gb0+b)*T_ + c0 + t_loc)*32 + q*8);
            *(uint4*)((char*)fch + uu*16) = v;
        }
        __syncthreads();                                // staging + flush drained here (once/chunk)

        // preload af0 for tc=0
        if (act){
            const unsigned short* fb = fch + 0*128 + ar*32 + lg*4;
            s16x4 lo = *(const s16x4*)fb, hi = *(const s16x4*)(fb + 16);
            af0 = (s16x8){lo[0],lo[1],lo[2],lo[3],hi[0],hi[1],hi[2],hi[3]};
        }

        for (int tc = 0; tc < CH_; ++tc){
            const int t = c0 + tc;
            const int cur = t & 1;
            const unsigned short* hb = lbuf[cur];

            s16x8 af1, af2, af3, af4;
            if (act){
                const char* bp = (const char*)hb + ar*288 + lg*8;
                s16x4 a1l = *(const s16x4*)(bp +   0), a1h = *(const s16x4*)(bp +  32);
                s16x4 a2l = *(const s16x4*)(bp +  64), a2h = *(const s16x4*)(bp +  96);
                s16x4 a3l = *(const s16x4*)(bp + 128), a3h = *(const s16x4*)(bp + 160);
                s16x4 a4l = *(const s16x4*)(bp + 192), a4h = *(const s16x4*)(bp + 224);
                af1 = (s16x8){a1l[0],a1l[1],a1l[2],a1l[3],a1h[0],a1h[1],a1h[2],a1h[3]};
                af2 = (s16x8){a2l[0],a2l[1],a2l[2],a2l[3],a2h[0],a2h[1],a2h[2],a2h[3]};
                af3 = (s16x8){a3l[0],a3l[1],a3l[2],a3l[3],a3h[0],a3h[1],a3h[2],a3h[3]};
                af4 = (s16x8){a4l[0],a4l[1],a4l[2],a4l[3],a4h[0],a4h[1],a4h[2],a4h[3]};
            } else {
                af1 = af2 = af3 = af4 = (s16x8){0,0,0,0,0,0,0,0};
            }

            // af0 MFMAs first (prefetched, no wait); h-chains follow as reads land
            f32x4 aA0 = __builtin_amdgcn_mfma_f32_16x16x32_bf16(af0, bw[0][0], Z4, 0,0,0);
            f32x4 aA1 = __builtin_amdgcn_mfma_f32_16x16x32_bf16(af0, bw[1][0], Z4, 0,0,0);
            f32x4 aA2 = __builtin_amdgcn_mfma_f32_16x16x32_bf16(af0, bw[2][0], Z4, 0,0,0);
            f32x4 aA3 = __builtin_amdgcn_mfma_f32_16x16x32_bf16(af0, bw[3][0], Z4, 0,0,0);
            f32x4 aB0 = __builtin_amdgcn_mfma_f32_16x16x32_bf16(af3, bw[0][3], Z4, 0,0,0);
            f32x4 aB1 = __builtin_amdgcn_mfma_f32_16x16x32_bf16(af3, bw[1][3], Z4, 0,0,0);
            f32x4 aB2 = __builtin_amdgcn_mfma_f32_16x16x32_bf16(af3, bw[2][3], Z4, 0,0,0);
            f32x4 aB3 = __builtin_amdgcn_mfma_f32_16x16x32_bf16(af3, bw[3][3], Z4, 0,0,0);
            aA0 = __builtin_amdgcn_mfma_f32_16x16x32_bf16(af1, bw[0][1], aA0, 0,0,0);
            aA1 = __builtin_amdgcn_mfma_f32_16x16x32_bf16(af1, bw[1][1], aA1, 0,0,0);
            aA2 = __builtin_amdgcn_mfma_f32_16x16x32_bf16(af1, bw[2][1], aA2, 0,0,0);
            aA3 = __builtin_amdgcn_mfma_f32_16x16x32_bf16(af1, bw[3][1], aA3, 0,0,0);
            aB0 = __builtin_amdgcn_mfma_f32_16x16x32_bf16(af4, bw[0][4], aB0, 0,0,0);
            aB1 = __builtin_amdgcn_mfma_f32_16x16x32_bf16(af4, bw[1][4], aB1, 0,0,0);
            aB2 = __builtin_amdgcn_mfma_f32_16x16x32_bf16(af4, bw[2][4], aB2, 0,0,0);
            aB3 = __builtin_amdgcn_mfma_f32_16x16x32_bf16(af4, bw[3][4], aB3, 0,0,0);
            aA0 = __builtin_amdgcn_mfma_f32_16x16x32_bf16(af2, bw[0][2], aA0, 0,0,0);
            aA1 = __builtin_amdgcn_mfma_f32_16x16x32_bf16(af2, bw[1][2], aA1, 0,0,0);
            aA2 = __builtin_amdgcn_mfma_f32_16x16x32_bf16(af2, bw[2][2], aA2, 0,0,0);
            aA3 = __builtin_amdgcn_mfma_f32_16x16x32_bf16(af2, bw[3][2], aA3, 0,0,0);

            // prefetch af0 for next step (static chunk data; clamp at chunk edge)
            if (act){
                int tn = (tc < CH_-1) ? tc+1 : tc;
                const unsigned short* fb = fch + tn*128 + ar*32 + lg*4;
                s16x4 lo = *(const s16x4*)fb, hi = *(const s16x4*)(fb + 16);
                af0 = (s16x8){lo[0],lo[1],lo[2],lo[3],hi[0],hi[1],hi[2],hi[3]};
            }

            // y waves: y(t-1) from h(t-1) in lbuf[cur] -> ybuf slot tc
            if (w >= 6 && l < 32 && t > 0){
                int b = (w - 6)*2 + (l >> 4);
                s16x8 hv = *(const s16x8*)(hb + b*144 + (l & 15)*8);
                float y0 = 0.f, y1 = 0.f;
                #pragma unroll
                for (int e = 0; e < 8; ++e){
                    float hf = __uint_as_float(((unsigned)(unsigned short)hv[e]) << 16);
                    y0 = fmaf(hf, wly0[e], y0); y1 = fmaf(hf, wly1[e], y1);
                }
                #pragma unroll
                for (int m = 1; m < 16; m <<= 1){ y0 += __shfl_xor(y0, m); y1 += __shfl_xor(y1, m); }
                if ((l & 15) == 0){
                    float2 yv; yv.x = y0 + bl0; yv.y = y1 + bl1;
                    *(float2*)&ybuf[b*(2*CH_) + tc*2] = yv;
                }
            }

            // activations: this thread's (b,j) = (lg, nj)
            float gi = aA0[0] + aB0[0];
            float gf = aA1[0] + aB1[0];
            float gg = aA2[0] + aB2[0];
            float go = aA3[0] + aB3[0];
            float si = frcp(1.f + fexp2(fmaf(gi, -L2E, nLb0)));
            float sf = frcp(1.f + fexp2(fmaf(gf, -L2E, nLb1)));
            float so = frcp(1.f + fexp2(fmaf(go, -L2E, nLb3)));
            float eg = fexp2(fmaf(gg, 2.f*L2E, b2g));
            float tg_ = fmaf(-2.f, frcp(1.f + eg), 1.f);
            c = sf*c + si*tg_;
            float ec = fexp2(c * (2.f*L2E));
            float tc_ = fmaf(-2.f, frcp(1.f + ec), 1.f);
            float h = so * tc_;

            // write h (bf16) for next step: row lg, col j
            unsigned hp;
            asm("v_cvt_pk_bf16_f32 %0, %1, %1" : "=v"(hp) : "v"(h));
            ((unsigned short*)lbuf[cur ^ 1])[lg*144 + nj] = (unsigned short)hp;

            __syncthreads();
        }
    }

    // ---- final flush: chunk T_/CH_-1 (slots 0..CH_-1 = y(T_-CH_-1 .. T_-2)) ----
    {
        const int c0p = T_ - CH_;
        int b = tid >> 7, i = tid & 127;
        long tg = (long)c0p + 2*i - 1;
        const float* src = &ybuf[b*(2*CH_) + i*4];
        float2 v0 = *(const float2*)(src);
        float2 v1 = *(const float2*)(src + 2);
        float* dst = &out[((long)(gb0+b)*T_ + tg)*2];
        *(float2*)dst = v0; *(float2*)(dst + 2) = v1;
    }
    // epilogue: y(T-1); h(T-1) sits in lbuf[0] (T_ even)
    if (w >= 6 && l < 32){
        int b = (w - 6)*2 + (l >> 4);
        const unsigned short* hb = lbuf[0];
        s16x8 hv = *(const s16x8*)(hb + b*144 + (l & 15)*8);
        float y0 = 0.f, y1 = 0.f;
        #pragma unroll
        for (int e = 0; e < 8; ++e){
            float hf = __uint_as_float(((unsigned)(unsigned short)hv[e]) << 16);
            y0 = fmaf(hf, wly0[e], y0); y1 = fmaf(hf, wly1[e], y1);
        }
        #pragma unroll
        for (int m = 1; m < 16; m <<= 1){ y0 += __shfl_xor(y0, m); y1 += __shfl_xor(y1, m); }
        if ((l & 15) == 0){
            float2 yv; yv.x = y0 + bl0; yv.y = y1 + bl1;
            *(float2*)&out[((long)(gb0 + b)*T_ + (T_-1))*2] = yv;
        }
    }
}

extern "C" void kernel_launch(void* const* d_in, const int* in_sizes, int n_in,
                              void* d_out, int out_size, void* d_ws, size_t ws_size,
                              hipStream_t stream)
{
    const float* x     = (const float*)d_in[0];
    const float* u     = (const float*)d_in[1];
    const float* dtp   = (const float*)d_in[2];
    const float* theta = (const float*)d_in[3];
    const float* He    = (const float*)d_in[4];
    const float* taue  = (const float*)d_in[5];
    const float* Hi    = (const float*)d_in[6];
    const float* taui  = (const float*)d_in[7];
    const float* l1    = (const float*)d_in[8];
    const float* l2    = (const float*)d_in[9];
    const float* l3    = (const float*)d_in[10];
    const float* l4    = (const float*)d_in[11];
    const float* Cf    = (const float*)d_in[12];
    const float* Cl    = (const float*)d_in[13];
    const float* Cu    = (const float*)d_in[14];
    const float* Cb    = (const float*)d_in[15];
    const float* Wih   = (const float*)d_in[16];
    const float* Whh   = (const float*)d_in[17];
    const float* bih   = (const float*)d_in[18];
    const float* bhh   = (const float*)d_in[19];
    const float* Wlin  = (const float*)d_in[20];
    const float* blin  = (const float*)d_in[21];

    unsigned short* feats = (unsigned short*)d_ws;   // B*T*32 bf16 = 16 MiB

    k_feats<<<(B_*T_)/256, 256, 0, stream>>>(x,u,dtp,theta,He,taue,Hi,taui,
                                             l1,l2,l3,l4,Cf,Cl,Cu,Cb,feats);
    k_scan<<<16, 512, 0, stream>>>(feats, Wih, Whh, bih, bhh, Wlin, blin, (float*)d_out);
}

// Round 4
// 2784.733 us; speedup vs baseline: 1.3211x; 1.2418x over previous
//
#include <hip/hip_runtime.h>

#define B_   64
#define T_   4096
#define HID_ 128
#define CH_  256   // steps per feats chunk (T_ % CH_ == 0, CH_ even)

typedef float f32x4 __attribute__((ext_vector_type(4)));
typedef short s16x8 __attribute__((ext_vector_type(8)));
typedef short s16x4 __attribute__((ext_vector_type(4)));

__device__ __forceinline__ float fexp2(float x){ float r; asm("v_exp_f32 %0, %1":"=v"(r):"v"(x)); return r; }
__device__ __forceinline__ float frcp (float x){ float r; asm("v_rcp_f32 %0, %1":"=v"(r):"v"(x)); return r; }
__device__ __forceinline__ unsigned short f2bf(float f){
    unsigned u = __float_as_uint(f);
    u += 0x7FFFu + ((u >> 16) & 1u);      // round-to-nearest-even
    return (unsigned short)(u >> 16);
}
__device__ __forceinline__ float sigf(float x){
    return frcp(1.0f + fexp2(-1.44269504089f * x));
}

// ---------------- Phase 1: ODE features -> feats[B][T][32] bf16 (PERMUTED) ----
// Within each 32-element row, slot s (0..3), elem e (0..7) holds feature
// j = s*4 + (e&3) + ((e>>2)<<4)  -> each MFMA lane's 8 A-elements are one 16B unit.
__global__ __launch_bounds__(256) void k_feats(
    const float* __restrict__ x, const float* __restrict__ u,
    const float* __restrict__ dtp, const float* __restrict__ theta,
    const float* __restrict__ He, const float* __restrict__ taue,
    const float* __restrict__ Hi, const float* __restrict__ taui,
    const float* __restrict__ l1, const float* __restrict__ l2,
    const float* __restrict__ l3, const float* __restrict__ l4,
    const float* __restrict__ Cf, const float* __restrict__ Cl,
    const float* __restrict__ Cu, const float* __restrict__ Cb,
    unsigned short* __restrict__ feats)
{
    long idx = (long)blockIdx.x * 256 + threadIdx.x;   // b*T + t
    const float dt = dtp[0];
    const float th00 = theta[0], th01 = theta[1], th10 = theta[2], th11 = theta[3];
    const float he = He[0], te = taue[0], hi = Hi[0], ti = taui[0];
    const float L1 = l1[0], L2v = l2[0], L3 = l3[0], L4 = l4[0];
    float cf[4], cl[4], cu[4], cb[4];
    #pragma unroll
    for (int i = 0; i < 4; ++i){ cf[i]=Cf[i]; cl[i]=Cl[i]; cu[i]=Cu[i]; cb[i]=Cb[i]; }
    const float ite  = 1.f/te, iti = 1.f/ti;
    const float He_te = he*ite, ite2 = ite*ite;
    const float Hi_ti = hi*iti, iti2 = iti*iti;

    float X[22];
    const float2* xr = (const float2*)(x + idx*22);
    #pragma unroll
    for (int i = 0; i < 11; ++i){ float2 v = xr[i]; X[2*i] = v.x; X[2*i+1] = v.y; }
    float2 uv = ((const float2*)u)[idx];

    float xt0 = X[0]*th00 + X[1]*th10;     // x[...,0,:] @ theta  ('btn,nm')
    float xt1 = X[0]*th01 + X[1]*th11;
    float ut0 = uv.x*th00 + uv.y*th10;
    float ut1 = uv.x*th01 + uv.y*th11;
    float s0 = sigf(xt0), s1 = sigf(xt1);

    // 'btn,mn->btm' : out[m] = sum_n M[m][n]*v[n]
    float Mf00 = cf[0]+cl[0]+L1, Mf01 = cf[1]+cl[1], Mf10 = cf[2]+cl[2], Mf11 = cf[3]+cl[3]+L1;
    float Af0 = Mf00*s0 + Mf01*s1, Af1 = Mf10*s0 + Mf11*s1;
    float Au0 = cu[0]*ut0 + cu[1]*ut1, Au1 = cu[2]*ut0 + cu[3]*ut1;
    float Mb00 = cb[0]+cl[0], Mb01 = cb[1]+cl[1], Mb10 = cb[2]+cl[2], Mb11 = cb[3]+cl[3];
    float Abl0 = Mb00*s0 + Mb01*s1, Abl1 = Mb10*s0 + Mb11*s1;
    float A30 = (Mb00+L3)*s0 + Mb01*s1,  A31 = Mb10*s0 + (Mb11+L3)*s1;

    float F[22];
    F[0]  = X[0]  + dt*(X[10]-X[12]);
    F[1]  = X[1]  + dt*(X[11]-X[13]);
    F[2]  = X[2]  + dt*X[8];
    F[3]  = X[3]  + dt*X[9];
    F[4]  = X[4]  + dt*X[10];
    F[5]  = X[5]  + dt*X[11];
    F[6]  = X[6]  + dt*X[12];
    F[7]  = X[7]  + dt*X[13];
    F[8]  = X[8]  + dt*(He_te*(Af0+Au0) - 2.f*X[8]*ite  - X[2]*ite2);
    F[9]  = X[9]  + dt*(He_te*(Af1+Au1) - 2.f*X[9]*ite  - X[3]*ite2);
    F[10] = X[10] + dt*(He_te*(Abl0 + L2v*sigf(X[6])) - 2.f*X[10]*ite - X[4]*ite2);
    F[11] = X[11] + dt*(He_te*(Abl1 + L2v*sigf(X[7])) - 2.f*X[11]*ite - X[5]*ite2);
    F[12] = X[12] + dt*(Hi_ti*L4*sigf(X[14]) - 2.f*X[12]*iti - X[6]*iti2);
    F[13] = X[13] + dt*(Hi_ti*L4*sigf(X[15]) - 2.f*X[13]*iti - X[7]*iti2);
    F[14] = X[14] + dt*X[16];
    F[15] = X[15] + dt*X[17];
    F[16] = X[16] + dt*(He_te*A30 - 2.f*X[16]*ite - X[14]*ite2);
    F[17] = X[17] + dt*(He_te*A31 - 2.f*X[17]*ite - X[15]*ite2);
    F[18] = X[18]; F[19] = X[19]; F[20] = X[20]; F[21] = X[21];

    unsigned short op[32];
    #pragma unroll
    for (int s = 0; s < 4; ++s){
        #pragma unroll
        for (int e = 0; e < 8; ++e){
            int j = s*4 + (e & 3) + ((e >> 2) << 4);
            op[s*8+e] = (j < 22) ? f2bf(F[j]) : (unsigned short)0;
        }
    }
    uint4* dst = (uint4*)(feats + idx*32);
    #pragma unroll
    for (int q = 0; q < 4; ++q){
        uint4 v;
        v.x = (unsigned)op[q*8+0] | ((unsigned)op[q*8+1] << 16);
        v.y = (unsigned)op[q*8+2] | ((unsigned)op[q*8+3] << 16);
        v.z = (unsigned)op[q*8+4] | ((unsigned)op[q*8+5] << 16);
        v.w = (unsigned)op[q*8+6] | ((unsigned)op[q*8+7] << 16);
        dst[q] = v;
    }
}

// ---------------- Phase 2: LSTM scan + fused W_lin head ----------------
// 16 blocks x 4 batches, 512 threads = 8 waves; wave w owns j in [w*16, w*16+16).
// Batch b at MFMA A-row 4b; D reg0 rows {0,4,8,12}. All fragments are single
// ds_read_b128 from permuted layouts (no assembly VALU). h stored permuted:
// hbuf[b(stride 288B)][khc*4+lg (16B unit)][hi*4+d], j = khc*32+lg*4+d+16*hi.
__global__ __launch_bounds__(512, 1) void k_scan(
    const unsigned short* __restrict__ feats,
    const float* __restrict__ Wih, const float* __restrict__ Whh,
    const float* __restrict__ bih, const float* __restrict__ bhh,
    const float* __restrict__ Wlin, const float* __restrict__ blin,
    float* __restrict__ out)
{
    __shared__ __align__(16) unsigned short fch[CH_ * 144];     // 288B/step, 72KB
    __shared__ __align__(16) unsigned short hbuf[2][4 * 144];   // 288B/batch, dbl-buf
    __shared__ __align__(16) float ybuf[4 * 2 * CH_];           // [b][slot][o]

    const int tid = threadIdx.x;
    const int w  = tid >> 6;
    const int l  = tid & 63;
    const int lm = l & 15;          // A/D column-lane
    const int lg = l >> 4;          // lane group: batch for activations, k-subgroup for A
    const int gb0 = blockIdx.x * 4;
    const int ar  = lm >> 2;        // A-row's batch (rows 0,4,8,12 real; others replicas)

    // zero h buffers (h(-1) = 0)
    for (int i = tid; i < (int)(sizeof(hbuf)/4); i += 512) ((unsigned*)hbuf)[i] = 0u;

    // ---- pack weight B-fragments into registers (bf16) ----
    const int nj = w*16 + lm;       // this thread's hidden index j
    s16x8 bw[4][5];
    #pragma unroll
    for (int t4 = 0; t4 < 4; ++t4){
        int n = t4*128 + nj;        // gate row: i,f,g,o blocks of 128
        #pragma unroll
        for (int kc = 0; kc < 5; ++kc){
            #pragma unroll
            for (int j = 0; j < 8; ++j){
                int k = kc*32 + lg*4 + (j & 3) + ((j >> 2) << 4);
                float wv = 0.f;
                if (kc == 0){ if (k < 22) wv = Wih[n*22 + k]; }
                else        { wv = Whh[n*128 + (k - 32)]; }
                bw[t4][kc][j] = (short)f2bf(wv);
            }
        }
    }
    const float L2E = 1.44269504089f;
    float nLb0, nLb1, nLb3, b2g;
    {
        float bi = bih[0*128+nj] + bhh[0*128+nj];
        float bf = bih[1*128+nj] + bhh[1*128+nj];
        float bg = bih[2*128+nj] + bhh[2*128+nj];
        float bo = bih[3*128+nj] + bhh[3*128+nj];
        nLb0 = -L2E*bi; nLb1 = -L2E*bf; nLb3 = -L2E*bo; b2g = 2.f*L2E*bg;
    }
    // y waves (6,7): W_lin in the SAME permutation as h storage.
    // lane s=(l&15) covers unit s: j(e) = (s>>2)*32 + (s&3)*4 + (e&3) + ((e>>2)<<4)
    float wly0[8], wly1[8];
    float bl0 = 0.f, bl1 = 0.f;
    if (w >= 6 && l < 32){
        int s = l & 15;
        #pragma unroll
        for (int e = 0; e < 8; ++e){
            int j = (s >> 2)*32 + (s & 3)*4 + (e & 3) + ((e >> 2) << 4);
            wly0[e] = Wlin[j]; wly1[e] = Wlin[128+j];
        }
        bl0 = blin[0]; bl1 = blin[1];
    } else {
        #pragma unroll
        for (int e = 0; e < 8; ++e){ wly0[e] = 0.f; wly1[e] = 0.f; }
    }

    // precomputed byte offsets
    const int abase = ar*288 + lg*16;                 // A-frag base within a hbuf buffer
    const int foff  = ar*64  + lg*16;                 // feats-frag offset within a fch step
    // h-write slot for j=nj in batch lg (u16 index):
    const int khc = nj >> 5, rr = nj & 31;
    const int hw  = lg*144 + ((khc*4 + ((rr >> 2) & 3))*8) + ((rr >> 4) << 2) + (rr & 3);

    // staging constants (thread-invariant)
    const int st_b = (tid & 15) >> 2, st_lg = tid & 3, st_t = tid >> 4;
    const unsigned short* st_src0 = feats + ((long)(gb0 + st_b)*T_ + st_t)*32 + st_lg*8;
    char* const st_dst0 = (char*)fch + st_t*288 + ((st_b*4 + st_lg)*16);

    const f32x4 Z4 = {0.f, 0.f, 0.f, 0.f};
    s16x8 af0;
    { // harmless init (overwritten after first staging)
        af0 = (s16x8){0,0,0,0,0,0,0,0};
    }
    float c = 0.f;

    for (int chk = 0; chk < T_/CH_; ++chk){
        const int c0 = chk * CH_;

        // ---- flush previous chunk's y buffer (slot s holds y(c0p + s - 1)) ----
        if (chk > 0){
            const int c0p = c0 - CH_;
            int b = tid >> 7, i = tid & 127;
            long tg = (long)c0p + 2*i - 1;
            const float* src = &ybuf[b*(2*CH_) + i*4];
            if (tg >= 0){
                float2 v0 = *(const float2*)(src);
                float2 v1 = *(const float2*)(src + 2);
                float* dst = &out[((long)(gb0+b)*T_ + tg)*2];
                *(float2*)dst = v0; *(float2*)(dst + 2) = v1;
            } else {
                float2 v1 = *(const float2*)(src + 2);
                *(float2*)&out[((long)(gb0+b)*T_)*2] = v1;
            }
        }

        // ---- stage feats chunk: global -> fch (permuted units, padded stride) ----
        {
            const unsigned short* sp = st_src0 + (long)c0*32;
            char* dp = st_dst0;
            #pragma unroll
            for (int it = 0; it < CH_/32; ++it){
                *(uint4*)dp = *(const uint4*)sp;
                sp += 32*32; dp += 32*288;
            }
        }
        __syncthreads();                                // staging drained (once/chunk)

        // preload af0 for tc=0
        af0 = *(const s16x8*)((const char*)fch + 0*288 + foff);

        #pragma unroll 1
        for (int tc = 0; tc < CH_; tc += 2){
            #pragma unroll
            for (int half = 0; half < 2; ++half){
                const int CUR = half, NXT = half ^ 1;
                const int tcc = tc + half;
                const unsigned short* hb = hbuf[CUR];

                __builtin_amdgcn_s_setprio(1);
                // kc=0 MFMAs first (af0 ready in regs) — covers h ds_read latency
                f32x4 a0 = __builtin_amdgcn_mfma_f32_16x16x32_bf16(af0, bw[0][0], Z4, 0,0,0);
                f32x4 a1 = __builtin_amdgcn_mfma_f32_16x16x32_bf16(af0, bw[1][0], Z4, 0,0,0);
                f32x4 a2 = __builtin_amdgcn_mfma_f32_16x16x32_bf16(af0, bw[2][0], Z4, 0,0,0);
                f32x4 a3 = __builtin_amdgcn_mfma_f32_16x16x32_bf16(af0, bw[3][0], Z4, 0,0,0);

                // h A-fragments: 4 single ds_read_b128 (permuted layout, no assembly)
                const char* bp = (const char*)hb + abase;
                s16x8 h1 = *(const s16x8*)(bp +   0);
                s16x8 h2 = *(const s16x8*)(bp +  64);
                s16x8 h3 = *(const s16x8*)(bp + 128);
                s16x8 h4 = *(const s16x8*)(bp + 192);

                a0 = __builtin_amdgcn_mfma_f32_16x16x32_bf16(h1, bw[0][1], a0, 0,0,0);
                a1 = __builtin_amdgcn_mfma_f32_16x16x32_bf16(h1, bw[1][1], a1, 0,0,0);
                a2 = __builtin_amdgcn_mfma_f32_16x16x32_bf16(h1, bw[2][1], a2, 0,0,0);
                a3 = __builtin_amdgcn_mfma_f32_16x16x32_bf16(h1, bw[3][1], a3, 0,0,0);
                a0 = __builtin_amdgcn_mfma_f32_16x16x32_bf16(h2, bw[0][2], a0, 0,0,0);
                a1 = __builtin_amdgcn_mfma_f32_16x16x32_bf16(h2, bw[1][2], a1, 0,0,0);
                a2 = __builtin_amdgcn_mfma_f32_16x16x32_bf16(h2, bw[2][2], a2, 0,0,0);
                a3 = __builtin_amdgcn_mfma_f32_16x16x32_bf16(h2, bw[3][2], a3, 0,0,0);
                a0 = __builtin_amdgcn_mfma_f32_16x16x32_bf16(h3, bw[0][3], a0, 0,0,0);
                a1 = __builtin_amdgcn_mfma_f32_16x16x32_bf16(h3, bw[1][3], a1, 0,0,0);
                a2 = __builtin_amdgcn_mfma_f32_16x16x32_bf16(h3, bw[2][3], a2, 0,0,0);
                a3 = __builtin_amdgcn_mfma_f32_16x16x32_bf16(h3, bw[3][3], a3, 0,0,0);
                a0 = __builtin_amdgcn_mfma_f32_16x16x32_bf16(h4, bw[0][4], a0, 0,0,0);
                a1 = __builtin_amdgcn_mfma_f32_16x16x32_bf16(h4, bw[1][4], a1, 0,0,0);
                a2 = __builtin_amdgcn_mfma_f32_16x16x32_bf16(h4, bw[2][4], a2, 0,0,0);
                a3 = __builtin_amdgcn_mfma_f32_16x16x32_bf16(h4, bw[3][4], a3, 0,0,0);
                __builtin_amdgcn_s_setprio(0);

                // prefetch af0 for next step (chunk-static; clamp at chunk edge)
                {
                    int tn = (tcc < CH_-1) ? tcc+1 : tcc;
                    af0 = *(const s16x8*)((const char*)fch + tn*288 + foff);
                }

                // y waves: y(t-1) from h(t-1) in hbuf[CUR] -> ybuf slot tcc
                if (w >= 6 && l < 32 && (c0 + tcc) > 0){
                    int b = (w - 6)*2 + (l >> 4);
                    s16x8 hv = *(const s16x8*)((const char*)hb + b*288 + (l & 15)*16);
                    float y0 = 0.f, y1 = 0.f;
                    #pragma unroll
                    for (int e = 0; e < 8; ++e){
                        float hf = __uint_as_float(((unsigned)(unsigned short)hv[e]) << 16);
                        y0 = fmaf(hf, wly0[e], y0); y1 = fmaf(hf, wly1[e], y1);
                    }
                    #pragma unroll
                    for (int m = 1; m < 16; m <<= 1){ y0 += __shfl_xor(y0, m); y1 += __shfl_xor(y1, m); }
                    if ((l & 15) == 0){
                        float2 yv; yv.x = y0 + bl0; yv.y = y1 + bl1;
                        *(float2*)&ybuf[b*(2*CH_) + tcc*2] = yv;
                    }
                }

                // activations: this thread's (b,j) = (lg, nj); gate pre-acts in reg0
                float si = frcp(1.f + fexp2(fmaf(a0[0], -L2E, nLb0)));
                float sf = frcp(1.f + fexp2(fmaf(a1[0], -L2E, nLb1)));
                float so = frcp(1.f + fexp2(fmaf(a3[0], -L2E, nLb3)));
                float eg = fexp2(fmaf(a2[0], 2.f*L2E, b2g));
                float tg_ = fmaf(-2.f, frcp(1.f + eg), 1.f);
                c = sf*c + si*tg_;
                float ec = fexp2(c * (2.f*L2E));
                float tc_ = fmaf(-2.f, frcp(1.f + ec), 1.f);
                float h = so * tc_;

                // write h (bf16) for next step at precomputed permuted slot
                unsigned hp;
                asm("v_cvt_pk_bf16_f32 %0, %1, %1" : "=v"(hp) : "v"(h));
                hbuf[NXT][hw] = (unsigned short)hp;

                __syncthreads();
            }
        }
    }

    // ---- final flush: last chunk (slots 0..CH_-1 = y(T_-CH_-1 .. T_-2)) ----
    {
        const int c0p = T_ - CH_;
        int b = tid >> 7, i = tid & 127;
        long tg = (long)c0p + 2*i - 1;
        const float* src = &ybuf[b*(2*CH_) + i*4];
        float2 v0 = *(const float2*)(src);
        float2 v1 = *(const float2*)(src + 2);
        float* dst = &out[((long)(gb0+b)*T_ + tg)*2];
        *(float2*)dst = v0; *(float2*)(dst + 2) = v1;
    }
    // epilogue: y(T-1); h(T-1) sits in hbuf[0] (T_ even)
    if (w >= 6 && l < 32){
        int b = (w - 6)*2 + (l >> 4);
        s16x8 hv = *(const s16x8*)((const char*)hbuf[0] + b*288 + (l & 15)*16);
        float y0 = 0.f, y1 = 0.f;
        #pragma unroll
        for (int e = 0; e < 8; ++e){
            float hf = __uint_as_float(((unsigned)(unsigned short)hv[e]) << 16);
            y0 = fmaf(hf, wly0[e], y0); y1 = fmaf(hf, wly1[e], y1);
        }
        #pragma unroll
        for (int m = 1; m < 16; m <<= 1){ y0 += __shfl_xor(y0, m); y1 += __shfl_xor(y1, m); }
        if ((l & 15) == 0){
            float2 yv; yv.x = y0 + bl0; yv.y = y1 + bl1;
            *(float2*)&out[((long)(gb0 + b)*T_ + (T_-1))*2] = yv;
        }
    }
}

extern "C" void kernel_launch(void* const* d_in, const int* in_sizes, int n_in,
                              void* d_out, int out_size, void* d_ws, size_t ws_size,
                              hipStream_t stream)
{
    const float* x     = (const float*)d_in[0];
    const float* u     = (const float*)d_in[1];
    const float* dtp   = (const float*)d_in[2];
    const float* theta = (const float*)d_in[3];
    const float* He    = (const float*)d_in[4];
    const float* taue  = (const float*)d_in[5];
    const float* Hi    = (const float*)d_in[6];
    const float* taui  = (const float*)d_in[7];
    const float* l1    = (const float*)d_in[8];
    const float* l2    = (const float*)d_in[9];
    const float* l3    = (const float*)d_in[10];
    const float* l4    = (const float*)d_in[11];
    const float* Cf    = (const float*)d_in[12];
    const float* Cl    = (const float*)d_in[13];
    const float* Cu    = (const float*)d_in[14];
    const float* Cb    = (const float*)d_in[15];
    const float* Wih   = (const float*)d_in[16];
    const float* Whh   = (const float*)d_in[17];
    const float* bih   = (const float*)d_in[18];
    const float* bhh   = (const float*)d_in[19];
    const float* Wlin  = (const float*)d_in[20];
    const float* blin  = (const float*)d_in[21];

    unsigned short* feats = (unsigned short*)d_ws;   // B*T*32 bf16 = 16 MiB (permuted)

    k_feats<<<(B_*T_)/256, 256, 0, stream>>>(x,u,dtp,theta,He,taue,Hi,taui,
                                             l1,l2,l3,l4,Cf,Cl,Cu,Cb,feats);
    k_scan<<<16, 512, 0, stream>>>(feats, Wih, Whh, bih, bhh, Wlin, blin, (float*)d_out);
}

// Round 5
// 1849.201 us; speedup vs baseline: 1.9894x; 1.5059x over previous
//
#include <hip/hip_runtime.h>

#define B_   64
#define T_   4096
#define HID_ 128
#define CH_  128   // steps per feats chunk (T_ % CH_ == 0, CH_ % 64 == 0)

typedef float f32x4 __attribute__((ext_vector_type(4)));
typedef short s16x8 __attribute__((ext_vector_type(8)));
typedef short s16x4 __attribute__((ext_vector_type(4)));

__device__ __forceinline__ float fexp2(float x){ float r; asm("v_exp_f32 %0, %1":"=v"(r):"v"(x)); return r; }
__device__ __forceinline__ float frcp (float x){ float r; asm("v_rcp_f32 %0, %1":"=v"(r):"v"(x)); return r; }
__device__ __forceinline__ unsigned short f2bf(float f){
    unsigned u = __float_as_uint(f);
    u += 0x7FFFu + ((u >> 16) & 1u);      // round-to-nearest-even
    return (unsigned short)(u >> 16);
}
__device__ __forceinline__ float sigf(float x){
    return frcp(1.0f + fexp2(-1.44269504089f * x));
}

// ---------------- Phase 1: ODE features -> feats[B][T][32] bf16 (PERMUTED) ----
// Within each 32-element row, slot s (0..3), elem e (0..7) holds feature
// j = s*4 + (e&3) + ((e>>2)<<4)  -> each MFMA lane's 8 A-elements are one 16B unit.
__global__ __launch_bounds__(256) void k_feats(
    const float* __restrict__ x, const float* __restrict__ u,
    const float* __restrict__ dtp, const float* __restrict__ theta,
    const float* __restrict__ He, const float* __restrict__ taue,
    const float* __restrict__ Hi, const float* __restrict__ taui,
    const float* __restrict__ l1, const float* __restrict__ l2,
    const float* __restrict__ l3, const float* __restrict__ l4,
    const float* __restrict__ Cf, const float* __restrict__ Cl,
    const float* __restrict__ Cu, const float* __restrict__ Cb,
    unsigned short* __restrict__ feats)
{
    long idx = (long)blockIdx.x * 256 + threadIdx.x;   // b*T + t
    const float dt = dtp[0];
    const float th00 = theta[0], th01 = theta[1], th10 = theta[2], th11 = theta[3];
    const float he = He[0], te = taue[0], hi = Hi[0], ti = taui[0];
    const float L1 = l1[0], L2v = l2[0], L3 = l3[0], L4 = l4[0];
    float cf[4], cl[4], cu[4], cb[4];
    #pragma unroll
    for (int i = 0; i < 4; ++i){ cf[i]=Cf[i]; cl[i]=Cl[i]; cu[i]=Cu[i]; cb[i]=Cb[i]; }
    const float ite  = 1.f/te, iti = 1.f/ti;
    const float He_te = he*ite, ite2 = ite*ite;
    const float Hi_ti = hi*iti, iti2 = iti*iti;

    float X[22];
    const float2* xr = (const float2*)(x + idx*22);
    #pragma unroll
    for (int i = 0; i < 11; ++i){ float2 v = xr[i]; X[2*i] = v.x; X[2*i+1] = v.y; }
    float2 uv = ((const float2*)u)[idx];

    float xt0 = X[0]*th00 + X[1]*th10;     // x[...,0,:] @ theta  ('btn,nm')
    float xt1 = X[0]*th01 + X[1]*th11;
    float ut0 = uv.x*th00 + uv.y*th10;
    float ut1 = uv.x*th01 + uv.y*th11;
    float s0 = sigf(xt0), s1 = sigf(xt1);

    // 'btn,mn->btm' : out[m] = sum_n M[m][n]*v[n]
    float Mf00 = cf[0]+cl[0]+L1, Mf01 = cf[1]+cl[1], Mf10 = cf[2]+cl[2], Mf11 = cf[3]+cl[3]+L1;
    float Af0 = Mf00*s0 + Mf01*s1, Af1 = Mf10*s0 + Mf11*s1;
    float Au0 = cu[0]*ut0 + cu[1]*ut1, Au1 = cu[2]*ut0 + cu[3]*ut1;
    float Mb00 = cb[0]+cl[0], Mb01 = cb[1]+cl[1], Mb10 = cb[2]+cl[2], Mb11 = cb[3]+cl[3];
    float Abl0 = Mb00*s0 + Mb01*s1, Abl1 = Mb10*s0 + Mb11*s1;
    float A30 = (Mb00+L3)*s0 + Mb01*s1,  A31 = Mb10*s0 + (Mb11+L3)*s1;

    float F[22];
    F[0]  = X[0]  + dt*(X[10]-X[12]);
    F[1]  = X[1]  + dt*(X[11]-X[13]);
    F[2]  = X[2]  + dt*X[8];
    F[3]  = X[3]  + dt*X[9];
    F[4]  = X[4]  + dt*X[10];
    F[5]  = X[5]  + dt*X[11];
    F[6]  = X[6]  + dt*X[12];
    F[7]  = X[7]  + dt*X[13];
    F[8]  = X[8]  + dt*(He_te*(Af0+Au0) - 2.f*X[8]*ite  - X[2]*ite2);
    F[9]  = X[9]  + dt*(He_te*(Af1+Au1) - 2.f*X[9]*ite  - X[3]*ite2);
    F[10] = X[10] + dt*(He_te*(Abl0 + L2v*sigf(X[6])) - 2.f*X[10]*ite - X[4]*ite2);
    F[11] = X[11] + dt*(He_te*(Abl1 + L2v*sigf(X[7])) - 2.f*X[11]*ite - X[5]*ite2);
    F[12] = X[12] + dt*(Hi_ti*L4*sigf(X[14]) - 2.f*X[12]*iti - X[6]*iti2);
    F[13] = X[13] + dt*(Hi_ti*L4*sigf(X[15]) - 2.f*X[13]*iti - X[7]*iti2);
    F[14] = X[14] + dt*X[16];
    F[15] = X[15] + dt*X[17];
    F[16] = X[16] + dt*(He_te*A30 - 2.f*X[16]*ite - X[14]*ite2);
    F[17] = X[17] + dt*(He_te*A31 - 2.f*X[17]*ite - X[15]*ite2);
    F[18] = X[18]; F[19] = X[19]; F[20] = X[20]; F[21] = X[21];

    unsigned short op[32];
    #pragma unroll
    for (int s = 0; s < 4; ++s){
        #pragma unroll
        for (int e = 0; e < 8; ++e){
            int j = s*4 + (e & 3) + ((e >> 2) << 4);
            op[s*8+e] = (j < 22) ? f2bf(F[j]) : (unsigned short)0;
        }
    }
    uint4* dst = (uint4*)(feats + idx*32);
    #pragma unroll
    for (int q = 0; q < 4; ++q){
        uint4 v;
        v.x = (unsigned)op[q*8+0] | ((unsigned)op[q*8+1] << 16);
        v.y = (unsigned)op[q*8+2] | ((unsigned)op[q*8+3] << 16);
        v.z = (unsigned)op[q*8+4] | ((unsigned)op[q*8+5] << 16);
        v.w = (unsigned)op[q*8+6] | ((unsigned)op[q*8+7] << 16);
        dst[q] = v;
    }
}

// ---------------- Phase 2: LSTM scan, y via per-window MFMA GEMM ----------------
// 16 blocks x 4 batches, 512 threads = 8 waves; wave w owns j in [w*16, w*16+16).
// h history: hist[64 slots][4 b][144 shorts] (permuted units) — slot = t & 63.
// Step t reads A-frags from slot (t-1)&63, writes h to slot t&63. Every 64 steps,
// y(t) for the whole window is computed as one [256 x 128] @ [128 x 2] MFMA GEMM
// (A-rows = (b,t2) pairs read straight from hist) — no per-step y work at all.
__global__ __launch_bounds__(512, 1) void k_scan(
    const unsigned short* __restrict__ feats,
    const float* __restrict__ Wih, const float* __restrict__ Whh,
    const float* __restrict__ bih, const float* __restrict__ bhh,
    const float* __restrict__ Wlin, const float* __restrict__ blin,
    float* __restrict__ out)
{
    __shared__ __align__(16) unsigned short fch[CH_ * 144];   // 36.9KB feats chunk
    __shared__ __align__(16) unsigned short hist[64 * 576];   // 73.7KB h history

    const int tid = threadIdx.x;
    const int w  = tid >> 6;
    const int l  = tid & 63;
    const int lm = l & 15;          // A/D column-lane
    const int lg = l >> 4;          // lane group: batch for act, k-subgroup for frags
    const int gb0 = blockIdx.x * 4;
    const int ar  = lm >> 2;        // A-row's batch (rows 0,4,8,12 real)

    // zero hist (h(-1)=0 lives in slot 63; everything else overwritten in order)
    for (int i = tid; i < 64*576/2; i += 512) ((unsigned*)hist)[i] = 0u;

    // ---- pack recurrent weight B-fragments into registers (bf16) ----
    const int nj = w*16 + lm;       // this thread's hidden index j
    s16x8 bw[4][5];
    #pragma unroll
    for (int t4 = 0; t4 < 4; ++t4){
        int n = t4*128 + nj;        // gate row: i,f,g,o blocks of 128
        #pragma unroll
        for (int kc = 0; kc < 5; ++kc){
            #pragma unroll
            for (int j = 0; j < 8; ++j){
                int k = kc*32 + lg*4 + (j & 3) + ((j >> 2) << 4);
                float wv = 0.f;
                if (kc == 0){ if (k < 22) wv = Wih[n*22 + k]; }
                else        { wv = Whh[n*128 + (k - 32)]; }
                bw[t4][kc][j] = (short)f2bf(wv);
            }
        }
    }
    // ---- W_lin B-fragment (N cols: 0->o=0, 1->o=1, rest zero) ----
    s16x8 wlf[4];
    #pragma unroll
    for (int kc = 0; kc < 4; ++kc){
        #pragma unroll
        for (int j = 0; j < 8; ++j){
            int k = kc*32 + lg*4 + (j & 3) + ((j >> 2) << 4);
            wlf[kc][j] = (lm < 2) ? (short)f2bf(Wlin[lm*128 + k]) : (short)0;
        }
    }
    const float blv = blin[l & 1];  // used by lanes lm<2 in y-GEMM stores

    const float L2E = 1.44269504089f;
    float nLb0, nLb1, nLb3, b2g;
    {
        float bi = bih[0*128+nj] + bhh[0*128+nj];
        float bf = bih[1*128+nj] + bhh[1*128+nj];
        float bg = bih[2*128+nj] + bhh[2*128+nj];
        float bo = bih[3*128+nj] + bhh[3*128+nj];
        nLb0 = -L2E*bi; nLb1 = -L2E*bf; nLb3 = -L2E*bo; b2g = 2.f*L2E*bg;
    }

    // precomputed offsets (shorts)
    const int aoff = ar*144 + lg*8;                   // A-frag base within a hist slot
    const int foff = ar*64  + lg*16;                  // feats-frag byte offset within fch step
    const int khc = nj >> 5;
    const int hwoff = lg*144 + (khc*4 + ((nj >> 2) & 3))*8 + ((nj >> 4) & 1)*4 + (nj & 3);

    // staging constants
    const int st_b = (tid & 15) >> 2, st_lg = tid & 3, st_t = tid >> 4;
    const unsigned short* st_src0 = feats + ((long)(gb0 + st_b)*T_ + st_t)*32 + st_lg*8;
    char* const st_dst0 = (char*)fch + st_t*288 + ((st_b*4 + st_lg)*16);

    const f32x4 Z4 = {0.f, 0.f, 0.f, 0.f};
    s16x8 af0 = {0,0,0,0,0,0,0,0};
    float c = 0.f;

    for (int chk = 0; chk < T_/CH_; ++chk){
        const int c0 = chk * CH_;

        // ---- stage feats chunk: global -> fch ----
        {
            const unsigned short* sp = st_src0 + (long)c0*32;
            char* dp = st_dst0;
            #pragma unroll
            for (int it = 0; it < CH_/32; ++it){
                *(uint4*)dp = *(const uint4*)sp;
                sp += 32*32; dp += 32*288;
            }
        }
        __syncthreads();                               // staging (+hist zero, 1st iter)

        af0 = *(const s16x8*)((const char*)fch + foff);   // feats frag for tc=0

        for (int yw = 0; yw < CH_/64; ++yw){
            int cbase = 0, pbase = 63*576;

            for (int s = 0; s < 64; ++s){
                const int tc = yw*64 + s;

                // kc=0 MFMAs first (af0 in regs) — covers h ds_read latency
                f32x4 a0 = __builtin_amdgcn_mfma_f32_16x16x32_bf16(af0, bw[0][0], Z4, 0,0,0);
                f32x4 a1 = __builtin_amdgcn_mfma_f32_16x16x32_bf16(af0, bw[1][0], Z4, 0,0,0);
                f32x4 a2 = __builtin_amdgcn_mfma_f32_16x16x32_bf16(af0, bw[2][0], Z4, 0,0,0);
                f32x4 a3 = __builtin_amdgcn_mfma_f32_16x16x32_bf16(af0, bw[3][0], Z4, 0,0,0);

                // h A-fragments from previous slot: 4 single ds_read_b128
                const unsigned short* hp = hist + pbase + aoff;
                s16x8 h1 = *(const s16x8*)(hp +  0);
                s16x8 h2 = *(const s16x8*)(hp + 32);
                s16x8 h3 = *(const s16x8*)(hp + 64);
                s16x8 h4 = *(const s16x8*)(hp + 96);

                a0 = __builtin_amdgcn_mfma_f32_16x16x32_bf16(h1, bw[0][1], a0, 0,0,0);
                a1 = __builtin_amdgcn_mfma_f32_16x16x32_bf16(h1, bw[1][1], a1, 0,0,0);
                a2 = __builtin_amdgcn_mfma_f32_16x16x32_bf16(h1, bw[2][1], a2, 0,0,0);
                a3 = __builtin_amdgcn_mfma_f32_16x16x32_bf16(h1, bw[3][1], a3, 0,0,0);
                a0 = __builtin_amdgcn_mfma_f32_16x16x32_bf16(h2, bw[0][2], a0, 0,0,0);
                a1 = __builtin_amdgcn_mfma_f32_16x16x32_bf16(h2, bw[1][2], a1, 0,0,0);
                a2 = __builtin_amdgcn_mfma_f32_16x16x32_bf16(h2, bw[2][2], a2, 0,0,0);
                a3 = __builtin_amdgcn_mfma_f32_16x16x32_bf16(h2, bw[3][2], a3, 0,0,0);
                a0 = __builtin_amdgcn_mfma_f32_16x16x32_bf16(h3, bw[0][3], a0, 0,0,0);
                a1 = __builtin_amdgcn_mfma_f32_16x16x32_bf16(h3, bw[1][3], a1, 0,0,0);
                a2 = __builtin_amdgcn_mfma_f32_16x16x32_bf16(h3, bw[2][3], a2, 0,0,0);
                a3 = __builtin_amdgcn_mfma_f32_16x16x32_bf16(h3, bw[3][3], a3, 0,0,0);
                a0 = __builtin_amdgcn_mfma_f32_16x16x32_bf16(h4, bw[0][4], a0, 0,0,0);
                a1 = __builtin_amdgcn_mfma_f32_16x16x32_bf16(h4, bw[1][4], a1, 0,0,0);
                a2 = __builtin_amdgcn_mfma_f32_16x16x32_bf16(h4, bw[2][4], a2, 0,0,0);
                a3 = __builtin_amdgcn_mfma_f32_16x16x32_bf16(h4, bw[3][4], a3, 0,0,0);

                // prefetch feats frag for next step (chunk-static; clamp at edge)
                {
                    int tn = (tc < CH_-1) ? tc+1 : tc;
                    af0 = *(const s16x8*)((const char*)fch + tn*288 + foff);
                }

                // activations: this thread's (b,j) = (lg, nj); gate pre-acts in reg0
                float si = frcp(1.f + fexp2(fmaf(a0[0], -L2E, nLb0)));
                float sf = frcp(1.f + fexp2(fmaf(a1[0], -L2E, nLb1)));
                float so = frcp(1.f + fexp2(fmaf(a3[0], -L2E, nLb3)));
                float eg = fexp2(fmaf(a2[0], 2.f*L2E, b2g));
                float tg_ = fmaf(-2.f, frcp(1.f + eg), 1.f);
                c = sf*c + si*tg_;
                float ec = fexp2(c * (2.f*L2E));
                float tc_ = fmaf(-2.f, frcp(1.f + ec), 1.f);
                float h = so * tc_;

                // write h (bf16) into current history slot
                unsigned hp2;
                asm("v_cvt_pk_bf16_f32 %0, %1, %1" : "=v"(hp2) : "v"(h));
                hist[cbase + hwoff] = (unsigned short)hp2;

                __syncthreads();
                pbase = cbase; cbase += 576;
            }

            // ---- y-GEMM for this window: [256 rows x K=128] @ W_lin^T -> out ----
            {
                const int cY0 = c0 + yw*64;
                #pragma unroll
                for (int mt = 0; mt < 2; ++mt){
                    const int Mt = w*2 + mt;
                    // A-frag: row = Mt*16+lm -> (b=lm&3, t2=Mt*4+(lm>>2))
                    const unsigned short* ap = hist + (Mt*4 + (lm >> 2))*576 + (lm & 3)*144 + lg*8;
                    s16x8 q0 = *(const s16x8*)(ap +  0);
                    s16x8 q1 = *(const s16x8*)(ap + 32);
                    s16x8 q2 = *(const s16x8*)(ap + 64);
                    s16x8 q3 = *(const s16x8*)(ap + 96);
                    f32x4 acc = __builtin_amdgcn_mfma_f32_16x16x32_bf16(q0, wlf[0], Z4, 0,0,0);
                    acc = __builtin_amdgcn_mfma_f32_16x16x32_bf16(q1, wlf[1], acc, 0,0,0);
                    acc = __builtin_amdgcn_mfma_f32_16x16x32_bf16(q2, wlf[2], acc, 0,0,0);
                    acc = __builtin_amdgcn_mfma_f32_16x16x32_bf16(q3, wlf[3], acc, 0,0,0);
                    if (lm < 2){
                        const int t = cY0 + Mt*4 + lg;      // D row 4*lg+r -> b=r, t2=Mt*4+lg
                        #pragma unroll
                        for (int r = 0; r < 4; ++r)
                            out[((long)(gb0 + r)*T_ + t)*2 + lm] = acc[r] + blv;
                    }
                }
            }
            __syncthreads();   // hist reads done before next window overwrites
        }
    }
}

extern "C" void kernel_launch(void* const* d_in, const int* in_sizes, int n_in,
                              void* d_out, int out_size, void* d_ws, size_t ws_size,
                              hipStream_t stream)
{
    const float* x     = (const float*)d_in[0];
    const float* u     = (const float*)d_in[1];
    const float* dtp   = (const float*)d_in[2];
    const float* theta = (const float*)d_in[3];
    const float* He    = (const float*)d_in[4];
    const float* taue  = (const float*)d_in[5];
    const float* Hi    = (const float*)d_in[6];
    const float* taui  = (const float*)d_in[7];
    const float* l1    = (const float*)d_in[8];
    const float* l2    = (const float*)d_in[9];
    const float* l3    = (const float*)d_in[10];
    const float* l4    = (const float*)d_in[11];
    const float* Cf    = (const float*)d_in[12];
    const float* Cl    = (const float*)d_in[13];
    const float* Cu    = (const float*)d_in[14];
    const float* Cb    = (const float*)d_in[15];
    const float* Wih   = (const float*)d_in[16];
    const float* Whh   = (const float*)d_in[17];
    const float* bih   = (const float*)d_in[18];
    const float* bhh   = (const float*)d_in[19];
    const float* Wlin  = (const float*)d_in[20];
    const float* blin  = (const float*)d_in[21];

    unsigned short* feats = (unsigned short*)d_ws;   // B*T*32 bf16 = 16 MiB (permuted)

    k_feats<<<(B_*T_)/256, 256, 0, stream>>>(x,u,dtp,theta,He,taue,Hi,taui,
                                             l1,l2,l3,l4,Cf,Cl,Cu,Cb,feats);
    k_scan<<<16, 512, 0, stream>>>(feats, Wih, Whh, bih, bhh, Wlin, blin, (float*)d_out);
}